// Round 8
// baseline (383.894 us; speedup 1.0000x reference)
//
#include <hip/hip_runtime.h>
#include <hip/hip_bf16.h>

typedef __bf16 bf16_t;
typedef __attribute__((ext_vector_type(8))) __bf16 bf16x8;
typedef __attribute__((ext_vector_type(4))) float f32x4;

#define FD 1024
#define HD 256
#define GG 4096

// pack 4 f32 -> 4 OCP e4m3 bytes (v_cvt_pk_fp8_f32, gfx950 = OCP)
__device__ inline unsigned int pack4_fp8(float a, float b, float c, float d) {
    int v = __builtin_amdgcn_cvt_pk_fp8_f32(a, b, 0, false);
    v = __builtin_amdgcn_cvt_pk_fp8_f32(c, d, v, true);
    return (unsigned int)v;
}

// ---------------------------------------------------------------------------
// prep: w1t = ce_w1^T (fp32, coalesced CE dot); w2t8/w3t8 = fp8 N-major
// ---------------------------------------------------------------------------
__global__ __launch_bounds__(256) void prep_kernel(
    const float* __restrict__ ce_w1,   // [1024,256]
    const float* __restrict__ sf_w2,   // [256,256]
    const float* __restrict__ sf_w3,   // [256,128]
    float* __restrict__ w1t,           // [256,1024]  (may be null)
    unsigned int* __restrict__ w2t8,   // [256 n][256 k] fp8, as u32[16384]
    unsigned int* __restrict__ w3t8)   // [128 n][256 k] fp8, as u32[8192]
{
    int id = blockIdx.x * 256 + threadIdx.x;   // 0..262143
    if (w1t != nullptr) {
        int j = id >> 10, k = id & 1023;
        w1t[id] = ce_w1[k * 256 + j];
    }
    if (id < 16384) {   // w2: n = id>>6, k4 = (id&63)*4
        int n = id >> 6, k4 = (id & 63) << 2;
        w2t8[id] = pack4_fp8(sf_w2[(k4 + 0) * 256 + n], sf_w2[(k4 + 1) * 256 + n],
                             sf_w2[(k4 + 2) * 256 + n], sf_w2[(k4 + 3) * 256 + n]);
    }
    if (id < 8192) {    // w3: n = id>>6, k4 = (id&63)*4
        int n = id >> 6, k4 = (id & 63) << 2;
        w3t8[id] = pack4_fp8(sf_w3[(k4 + 0) * 128 + n], sf_w3[(k4 + 1) * 128 + n],
                             sf_w3[(k4 + 2) * 128 + n], sf_w3[(k4 + 3) * 128 + n]);
    }
}

// ---------------------------------------------------------------------------
// context encoder: one block per batch row; fp32 throughout.
// zpart[b][j] = z_c[b] @ sf_w1[2:] + sf_b1   (bias folded in)
// ---------------------------------------------------------------------------
__global__ __launch_bounds__(256) void ce_kernel(
    const float* __restrict__ features,   // [256,1024]
    const float* __restrict__ ce_w1,      // [1024,256] (fallback path)
    const float* __restrict__ w1t,        // [256,1024] or null
    const float* __restrict__ ce_b1,
    const float* __restrict__ ce_w2, const float* __restrict__ ce_b2,
    const float* __restrict__ ce_w3, const float* __restrict__ ce_b3,
    const float* __restrict__ sf_w1,      // [66,256]
    const float* __restrict__ sf_b1,
    float* __restrict__ zpart)            // [256,256]
{
    __shared__ float fs[FD];
    __shared__ float z1[HD];
    __shared__ float z2[HD / 2];
    __shared__ float zc[64];
    const int b = blockIdx.x, t = threadIdx.x;

    #pragma unroll
    for (int i = 0; i < 4; ++i) fs[t + i * 256] = features[b * FD + t + i * 256];
    __syncthreads();

    // layer 1: 1024 -> 256
    {
        float s = ce_b1[t];
        if (w1t != nullptr) {
            const float4* wr = reinterpret_cast<const float4*>(w1t + t * FD);
            #pragma unroll 4
            for (int k = 0; k < FD / 4; ++k) {
                float4 w = wr[k];
                const float4 f = *reinterpret_cast<const float4*>(&fs[k * 4]);
                s = fmaf(w.x, f.x, s);
                s = fmaf(w.y, f.y, s);
                s = fmaf(w.z, f.z, s);
                s = fmaf(w.w, f.w, s);
            }
        } else {
            #pragma unroll 8
            for (int k = 0; k < FD; ++k) s = fmaf(fs[k], ce_w1[k * 256 + t], s);
        }
        z1[t] = s > 0.f ? s : 0.f;
    }
    __syncthreads();

    // layer 2: 256 -> 128
    if (t < 128) {
        float s = ce_b2[t];
        #pragma unroll 8
        for (int k = 0; k < 256; ++k) s = fmaf(z1[k], ce_w2[k * 128 + t], s);
        z2[t] = s > 0.f ? s : 0.f;
    }
    __syncthreads();

    // layer 3: 128 -> 64 (no relu)
    if (t < 64) {
        float s = ce_b3[t];
        #pragma unroll 8
        for (int k = 0; k < 128; ++k) s = fmaf(z2[k], ce_w3[k * 64 + t], s);
        zc[t] = s;
    }
    __syncthreads();

    // zpart = zc @ sf_w1[2:] + sf_b1
    {
        float s = sf_b1[t];
        #pragma unroll 8
        for (int k = 0; k < 64; ++k) s = fmaf(zc[k], sf_w1[(2 + k) * 256 + t], s);
        zpart[b * HD + t] = s;
    }
}

// ---------------------------------------------------------------------------
// fused field MLP, fp8, weight-stationary, cross-tile pipeline, 16 WAVES:
//   grid=256 (1 block/CU), 1024 thr (16 waves, 4/SIMD -> needs <=128 VGPR).
//   Phase p:  GEMM1(tile p)  ||  GEMM2(tile p-1)  ||  final-store(tile p-2)
//   GEMM1: wave = 32 rows x 32 cols (2 rgrp x 8 cgrp); b1f 32 VGPR.
//   GEMM2: wave = 16 h2-rows x 32 w3-cols (4 rq x 4 cgrp); w3f 32 VGPR.
//   Meshgrid structure: x0 constant per tile (1 scalar load/phase),
//   x1 per-thread tile-invariant -> h1 build = 1 fma/element.
// ---------------------------------------------------------------------------
__global__ __launch_bounds__(1024, 4) void field_kernel(
    const float* __restrict__ coords,   // [4096,2]
    const float* __restrict__ sf_w1,    // [66,256] rows 0,1 used
    const float* __restrict__ zpart,    // [256,256]
    const unsigned char* __restrict__ w2t8, // [256 n][256 k] fp8
    const float* __restrict__ sf_b2,    // [256]
    const unsigned char* __restrict__ w3t8, // [128 n][256 k] fp8
    const float* __restrict__ sf_b3,    // [128]
    const float* __restrict__ sf_w4,    // [128]
    const float* __restrict__ sf_b4,    // [1]
    float* __restrict__ out)            // [256,4096]
{
    __shared__ __attribute__((aligned(128))) unsigned char h1[2][64 * 256];  // 2x16KB
    __shared__ __attribute__((aligned(128))) unsigned char h2[2][64 * 256];  // 2x16KB
    __shared__ float partials[2][64][20];                                    // 10 KB

    const int b = blockIdx.x;
    const int tid = threadIdx.x;
    const int wid = tid >> 6;          // 0..15
    const int lane = tid & 63;
    const int l15 = lane & 15;
    const int l4 = lane >> 4;

    // ---- GEMM1 tiling: 2 row-groups x 8 col-groups ----
    const int cg1 = wid & 7;           // cols cg1*32 .. +31
    const int rg1 = wid >> 3;          // rows rg1*32 .. +31
    long b1f[8][2];
    #pragma unroll
    for (int ks = 0; ks < 8; ++ks)
        #pragma unroll
        for (int n = 0; n < 2; ++n)
            b1f[ks][n] = *reinterpret_cast<const long*>(
                &w2t8[(cg1 * 32 + n * 16 + l15) * 256 + ks * 32 + l4 * 8]);

    // ---- GEMM2 tiling: 4 row-quarters x 4 col-groups ----
    const int cgrp = wid & 3;          // w3 cols cgrp*32 .. +31
    const int rq = wid >> 2;           // h2 rows rq*16 .. +15
    long w3f[8][2];
    #pragma unroll
    for (int ks = 0; ks < 8; ++ks)
        #pragma unroll
        for (int cb = 0; cb < 2; ++cb)
            w3f[ks][cb] = *reinterpret_cast<const long*>(
                &w3t8[(cgrp * 32 + cb * 16 + l15) * 256 + ks * 32 + l4 * 8]);

    const float b4v = sf_b4[0];

    // ---- h1-build constants: thread builds 8B chunk kc of rows rbase, rbase+32 ----
    const int kc = tid & 31;
    const int rbase = tid >> 5;        // 0..31
    f32x4 zp[2];
    bf16x8 wap, wbp;
    #pragma unroll
    for (int h = 0; h < 2; ++h)
        zp[h] = *reinterpret_cast<const f32x4*>(&zpart[b * HD + kc * 8 + h * 4]);
    #pragma unroll
    for (int j = 0; j < 8; ++j) {
        wap[j] = (bf16_t)sf_w1[kc * 8 + j];
        wbp[j] = (bf16_t)sf_w1[HD + kc * 8 + j];
    }
    // x1 per thread (tile-invariant, from meshgrid structure): y of g=row
    float xv0 = coords[2 * rbase + 1];
    float xv1 = coords[2 * (32 + rbase) + 1];

    // build h1 tile given tile-constant x0
    auto build_store = [&](float x0, unsigned char* buf) {
        float zc[8];
        #pragma unroll
        for (int h = 0; h < 2; ++h)
            #pragma unroll
            for (int j = 0; j < 4; ++j)
                zc[h * 4 + j] = fmaf(x0, (float)wap[h * 4 + j], zp[h][j]);
        #pragma unroll
        for (int it = 0; it < 2; ++it) {
            int row = it * 32 + rbase;
            float xv = it ? xv1 : xv0;
            float s[8];
            #pragma unroll
            for (int j = 0; j < 8; ++j) {
                float v = fmaf(xv, (float)wbp[j], zc[j]);
                s[j] = v > 0.f ? v : 0.f;
            }
            uint2 pk;
            pk.x = pack4_fp8(s[0], s[1], s[2], s[3]);
            pk.y = pack4_fp8(s[4], s[5], s[6], s[7]);
            *reinterpret_cast<uint2*>(&buf[row * 256 + ((kc ^ (row & 15)) << 3)]) = pk;
        }
    };

    // prologue: tile 0 into h1[0]
    build_store(coords[0], h1[0]);
    __syncthreads();

    #pragma unroll 1
    for (int ph = 0; ph < 66; ++ph) {
        const bool doG1 = (ph < 64);
        const bool doG2 = (ph >= 1) && (ph < 65);
        const unsigned char* h1cur = h1[ph & 1];
        const unsigned char* h2prev = h2[(ph + 1) & 1];   // tile ph-1
        unsigned char* h2cur = h2[ph & 1];                // tile ph

        // tile-constant x0 for next tile (wave-uniform scalar load)
        float x0n = (ph < 63) ? coords[(ph + 1) * 128] : 0.f;

        f32x4 acc1[2][2] = {};
        f32x4 acc2[1][2] = {};

        if (doG1 && doG2) {
            // ---- fused: GEMM1(tile ph) + GEMM2(tile ph-1), interleaved ----
            #pragma unroll
            for (int ks = 0; ks < 8; ++ks) {
                const int ch = ((ks * 4 + l4) ^ l15) << 3;
                long a0 = *reinterpret_cast<const long*>(&h1cur[(rg1 * 32 + l15)      * 256 + ch]);
                long a1 = *reinterpret_cast<const long*>(&h1cur[(rg1 * 32 + 16 + l15) * 256 + ch]);
                long hb0 = *reinterpret_cast<const long*>(&h2prev[(rq * 16 + l15) * 256 + ch]);
                __builtin_amdgcn_s_setprio(1);
                #pragma unroll
                for (int n = 0; n < 2; ++n) {
                    acc1[0][n] = __builtin_amdgcn_mfma_f32_16x16x32_fp8_fp8(b1f[ks][n], a0, acc1[0][n], 0, 0, 0);
                    acc1[1][n] = __builtin_amdgcn_mfma_f32_16x16x32_fp8_fp8(b1f[ks][n], a1, acc1[1][n], 0, 0, 0);
                }
                #pragma unroll
                for (int cb = 0; cb < 2; ++cb)
                    acc2[0][cb] = __builtin_amdgcn_mfma_f32_16x16x32_fp8_fp8(w3f[ks][cb], hb0, acc2[0][cb], 0, 0, 0);
                __builtin_amdgcn_s_setprio(0);
            }
        } else if (doG1) {
            // ---- phase 0: GEMM1 only ----
            #pragma unroll
            for (int ks = 0; ks < 8; ++ks) {
                const int ch = ((ks * 4 + l4) ^ l15) << 3;
                long a0 = *reinterpret_cast<const long*>(&h1cur[(rg1 * 32 + l15)      * 256 + ch]);
                long a1 = *reinterpret_cast<const long*>(&h1cur[(rg1 * 32 + 16 + l15) * 256 + ch]);
                __builtin_amdgcn_s_setprio(1);
                #pragma unroll
                for (int n = 0; n < 2; ++n) {
                    acc1[0][n] = __builtin_amdgcn_mfma_f32_16x16x32_fp8_fp8(b1f[ks][n], a0, acc1[0][n], 0, 0, 0);
                    acc1[1][n] = __builtin_amdgcn_mfma_f32_16x16x32_fp8_fp8(b1f[ks][n], a1, acc1[1][n], 0, 0, 0);
                }
                __builtin_amdgcn_s_setprio(0);
            }
        } else if (doG2) {
            // ---- phase 64: GEMM2 only ----
            #pragma unroll
            for (int ks = 0; ks < 8; ++ks) {
                const int ch = ((ks * 4 + l4) ^ l15) << 3;
                long hb0 = *reinterpret_cast<const long*>(&h2prev[(rq * 16 + l15) * 256 + ch]);
                __builtin_amdgcn_s_setprio(1);
                #pragma unroll
                for (int cb = 0; cb < 2; ++cb)
                    acc2[0][cb] = __builtin_amdgcn_mfma_f32_16x16x32_fp8_fp8(w3f[ks][cb], hb0, acc2[0][cb], 0, 0, 0);
                __builtin_amdgcn_s_setprio(0);
            }
        }

        // ---- build h1 for tile ph+1 (VALU; overlaps MFMA drain) ----
        if (ph < 63) build_store(x0n, h1[(ph + 1) & 1]);

        // ---- GEMM1 epilogue: h2 = relu(acc1 + b2) -> h2cur (b32 writes) ----
        if (doG1) {
            #pragma unroll
            for (int n = 0; n < 2; ++n) {
                f32x4 b2v = *reinterpret_cast<const f32x4*>(&sf_b2[cg1 * 32 + n * 16 + l4 * 4]);
                #pragma unroll
                for (int m = 0; m < 2; ++m) {
                    int row = rg1 * 32 + m * 16 + l15;
                    int chunk = cg1 * 4 + n * 2 + (l4 >> 1);
                    float x0 = acc1[m][n][0] + b2v[0];
                    float x1 = acc1[m][n][1] + b2v[1];
                    float x2 = acc1[m][n][2] + b2v[2];
                    float x3 = acc1[m][n][3] + b2v[3];
                    x0 = x0 > 0.f ? x0 : 0.f;
                    x1 = x1 > 0.f ? x1 : 0.f;
                    x2 = x2 > 0.f ? x2 : 0.f;
                    x3 = x3 > 0.f ? x3 : 0.f;
                    *reinterpret_cast<unsigned int*>(
                        &h2cur[row * 256 + ((chunk ^ (row & 15)) << 3) + (l4 & 1) * 4]) =
                        pack4_fp8(x0, x1, x2, x3);
                }
            }
        }

        // ---- GEMM2 epilogue: relu + w4 partial dot -> partials[(ph-1)&1] ----
        if (doG2) {
            f32x4 b3v0 = *reinterpret_cast<const f32x4*>(&sf_b3[cgrp * 32 + l4 * 4]);
            f32x4 b3v1 = *reinterpret_cast<const f32x4*>(&sf_b3[cgrp * 32 + 16 + l4 * 4]);
            f32x4 w4v0 = *reinterpret_cast<const f32x4*>(&sf_w4[cgrp * 32 + l4 * 4]);
            f32x4 w4v1 = *reinterpret_cast<const f32x4*>(&sf_w4[cgrp * 32 + 16 + l4 * 4]);
            float pp = 0.f;
            #pragma unroll
            for (int i = 0; i < 4; ++i) {
                float v0 = acc2[0][0][i] + b3v0[i];
                float v1 = acc2[0][1][i] + b3v1[i];
                v0 = v0 > 0.f ? v0 : 0.f;
                v1 = v1 > 0.f ? v1 : 0.f;
                pp = fmaf(v0, w4v0[i], pp);
                pp = fmaf(v1, w4v1[i], pp);
            }
            partials[(ph - 1) & 1][rq * 16 + l15][cgrp * 4 + l4] = pp;
        }

        // ---- final store for tile ph-2 (wave 0; partials written phase ph-1) ----
        if (ph >= 2 && tid < 64) {
            const f32x4* pr = reinterpret_cast<const f32x4*>(&partials[ph & 1][tid][0]);
            f32x4 ss = pr[0] + pr[1] + pr[2] + pr[3];
            float s = ss[0] + ss[1] + ss[2] + ss[3] + b4v;
            out[b * GG + (ph - 2) * 64 + tid] = 1.f / (1.f + __expf(-s));
        }

        __syncthreads();
    }
}

// ---------------------------------------------------------------------------
extern "C" void kernel_launch(void* const* d_in, const int* in_sizes, int n_in,
                              void* d_out, int out_size, void* d_ws, size_t ws_size,
                              hipStream_t stream)
{
    const float* features = (const float*)d_in[0];
    const float* coords   = (const float*)d_in[1];
    const float* ce_w1 = (const float*)d_in[2];
    const float* ce_b1 = (const float*)d_in[3];
    const float* ce_w2 = (const float*)d_in[4];
    const float* ce_b2 = (const float*)d_in[5];
    const float* ce_w3 = (const float*)d_in[6];
    const float* ce_b3 = (const float*)d_in[7];
    const float* sf_w1 = (const float*)d_in[8];
    const float* sf_b1 = (const float*)d_in[9];
    const float* sf_w2 = (const float*)d_in[10];
    const float* sf_b2 = (const float*)d_in[11];
    const float* sf_w3 = (const float*)d_in[12];
    const float* sf_b3 = (const float*)d_in[13];
    const float* sf_w4 = (const float*)d_in[14];
    const float* sf_b4 = (const float*)d_in[15];
    float* out = (float*)d_out;

    char* ws = (char*)d_ws;
    float*        zpart = (float*)ws;                             // 256 KB
    unsigned int* w2t8  = (unsigned int*)(ws + 262144);           //  64 KB
    unsigned int* w3t8  = (unsigned int*)(ws + 262144 + 65536);   //  32 KB
    float*        w1t   = (float*)(ws + 262144 + 65536 + 32768);  //   1 MB (optional)
    const size_t need_w1t = (size_t)(262144 + 65536 + 32768) + (size_t)FD * HD * 4;
    float* w1t_ptr = (ws_size >= need_w1t) ? w1t : nullptr;

    hipLaunchKernelGGL(prep_kernel, dim3(1024), dim3(256), 0, stream,
                       ce_w1, sf_w2, sf_w3, w1t_ptr, w2t8, w3t8);
    hipLaunchKernelGGL(ce_kernel, dim3(256), dim3(256), 0, stream,
                       features, ce_w1, w1t_ptr, ce_b1, ce_w2, ce_b2, ce_w3, ce_b3,
                       sf_w1, sf_b1, zpart);
    hipLaunchKernelGGL(field_kernel, dim3(256), dim3(1024), 0, stream,
                       coords, sf_w1, zpart,
                       (const unsigned char*)w2t8, sf_b2,
                       (const unsigned char*)w3t8, sf_b3, sf_w4, sf_b4, out);
}

// Round 9
// 258.025 us; speedup vs baseline: 1.4878x; 1.4878x over previous
//
#include <hip/hip_runtime.h>
#include <hip/hip_bf16.h>

typedef __bf16 bf16_t;
typedef __attribute__((ext_vector_type(8))) __bf16 bf16x8;
typedef __attribute__((ext_vector_type(4))) float f32x4;

#define FD 1024
#define HD 256
#define GG 4096

// pack 4 f32 -> 4 OCP e4m3 bytes (v_cvt_pk_fp8_f32, gfx950 = OCP)
__device__ inline unsigned int pack4_fp8(float a, float b, float c, float d) {
    int v = __builtin_amdgcn_cvt_pk_fp8_f32(a, b, 0, false);
    v = __builtin_amdgcn_cvt_pk_fp8_f32(c, d, v, true);
    return (unsigned int)v;
}

// ---------------------------------------------------------------------------
// prep: w1t = ce_w1^T (fp32, coalesced CE dot); w2t8/w3t8 = fp8 N-major
// ---------------------------------------------------------------------------
__global__ __launch_bounds__(256) void prep_kernel(
    const float* __restrict__ ce_w1,   // [1024,256]
    const float* __restrict__ sf_w2,   // [256,256]
    const float* __restrict__ sf_w3,   // [256,128]
    float* __restrict__ w1t,           // [256,1024]  (may be null)
    unsigned int* __restrict__ w2t8,   // [256 n][256 k] fp8, as u32[16384]
    unsigned int* __restrict__ w3t8)   // [128 n][256 k] fp8, as u32[8192]
{
    int id = blockIdx.x * 256 + threadIdx.x;   // 0..262143
    if (w1t != nullptr) {
        int j = id >> 10, k = id & 1023;
        w1t[id] = ce_w1[k * 256 + j];
    }
    if (id < 16384) {   // w2: n = id>>6, k4 = (id&63)*4
        int n = id >> 6, k4 = (id & 63) << 2;
        w2t8[id] = pack4_fp8(sf_w2[(k4 + 0) * 256 + n], sf_w2[(k4 + 1) * 256 + n],
                             sf_w2[(k4 + 2) * 256 + n], sf_w2[(k4 + 3) * 256 + n]);
    }
    if (id < 8192) {    // w3: n = id>>6, k4 = (id&63)*4
        int n = id >> 6, k4 = (id & 63) << 2;
        w3t8[id] = pack4_fp8(sf_w3[(k4 + 0) * 128 + n], sf_w3[(k4 + 1) * 128 + n],
                             sf_w3[(k4 + 2) * 128 + n], sf_w3[(k4 + 3) * 128 + n]);
    }
}

// ---------------------------------------------------------------------------
// context encoder: one block per batch row; fp32 throughout.
// zpart[b][j] = z_c[b] @ sf_w1[2:] + sf_b1   (bias folded in)
// ---------------------------------------------------------------------------
__global__ __launch_bounds__(256) void ce_kernel(
    const float* __restrict__ features,   // [256,1024]
    const float* __restrict__ ce_w1,      // [1024,256] (fallback path)
    const float* __restrict__ w1t,        // [256,1024] or null
    const float* __restrict__ ce_b1,
    const float* __restrict__ ce_w2, const float* __restrict__ ce_b2,
    const float* __restrict__ ce_w3, const float* __restrict__ ce_b3,
    const float* __restrict__ sf_w1,      // [66,256]
    const float* __restrict__ sf_b1,
    float* __restrict__ zpart)            // [256,256]
{
    __shared__ float fs[FD];
    __shared__ float z1[HD];
    __shared__ float z2[HD / 2];
    __shared__ float zc[64];
    const int b = blockIdx.x, t = threadIdx.x;

    #pragma unroll
    for (int i = 0; i < 4; ++i) fs[t + i * 256] = features[b * FD + t + i * 256];
    __syncthreads();

    // layer 1: 1024 -> 256
    {
        float s = ce_b1[t];
        if (w1t != nullptr) {
            const float4* wr = reinterpret_cast<const float4*>(w1t + t * FD);
            #pragma unroll 4
            for (int k = 0; k < FD / 4; ++k) {
                float4 w = wr[k];
                const float4 f = *reinterpret_cast<const float4*>(&fs[k * 4]);
                s = fmaf(w.x, f.x, s);
                s = fmaf(w.y, f.y, s);
                s = fmaf(w.z, f.z, s);
                s = fmaf(w.w, f.w, s);
            }
        } else {
            #pragma unroll 8
            for (int k = 0; k < FD; ++k) s = fmaf(fs[k], ce_w1[k * 256 + t], s);
        }
        z1[t] = s > 0.f ? s : 0.f;
    }
    __syncthreads();

    // layer 2: 256 -> 128
    if (t < 128) {
        float s = ce_b2[t];
        #pragma unroll 8
        for (int k = 0; k < 256; ++k) s = fmaf(z1[k], ce_w2[k * 128 + t], s);
        z2[t] = s > 0.f ? s : 0.f;
    }
    __syncthreads();

    // layer 3: 128 -> 64 (no relu)
    if (t < 64) {
        float s = ce_b3[t];
        #pragma unroll 8
        for (int k = 0; k < 128; ++k) s = fmaf(z2[k], ce_w3[k * 64 + t], s);
        zc[t] = s;
    }
    __syncthreads();

    // zpart = zc @ sf_w1[2:] + sf_b1
    {
        float s = sf_b1[t];
        #pragma unroll 8
        for (int k = 0; k < 64; ++k) s = fmaf(zc[k], sf_w1[(2 + k) * 256 + t], s);
        zpart[b * HD + t] = s;
    }
}

// ---------------------------------------------------------------------------
// fused field MLP, fp8, weight-stationary, cross-tile pipeline.
//   grid=512: block (2b+h) = batch b, tile half h (tiles h*32 .. h*32+31).
//   512 thr (8 waves). 74 KB LDS + 128 VGPR -> 2 blocks/CU co-resident
//   (16 waves/CU, 4/SIMD) for cross-block MFMA||VALU overlap.
//   Phase p:  GEMM1(tile p)  ||  GEMM2(tile p-1)  ||  final-store(tile p-2)
//   GEMM1: 2 rgrp x 4 cgrp waves (wave = 32 rows x 64 cols); b1f 64 VGPR.
//   GEMM2: 2 rhalf x 4 cgrp; w3f 32 VGPR.
//   LDS rows 256 B; 8B-chunk XOR swizzle chunk^=(row&15).
// ---------------------------------------------------------------------------
__global__ __launch_bounds__(512, 2) void field_kernel(
    const float* __restrict__ coords,   // [4096,2]
    const float* __restrict__ sf_w1,    // [66,256] rows 0,1 used
    const float* __restrict__ zpart,    // [256,256]
    const unsigned char* __restrict__ w2t8, // [256 n][256 k] fp8
    const float* __restrict__ sf_b2,    // [256]
    const unsigned char* __restrict__ w3t8, // [128 n][256 k] fp8
    const float* __restrict__ sf_b3,    // [128]
    const float* __restrict__ sf_w4,    // [128]
    const float* __restrict__ sf_b4,    // [1]
    float* __restrict__ out)            // [256,4096]
{
    __shared__ __attribute__((aligned(128))) unsigned char h1[2][64 * 256];  // 2x16KB
    __shared__ __attribute__((aligned(128))) unsigned char h2[2][64 * 256];  // 2x16KB
    __shared__ float partials[2][64][20];                                    // 10 KB

    const int bid = blockIdx.x;
    const int b = bid >> 1;            // batch row
    const int tbase = (bid & 1) * 32;  // tile half: tiles tbase .. tbase+31
    const int tid = threadIdx.x;
    const int wid = tid >> 6;
    const int lane = tid & 63;
    const int l15 = lane & 15;
    const int l4 = lane >> 4;

    // ---- resident weights ----
    // GEMM1 A-frags (w2^T): wave covers h2 cols cg1*64 .. +63 (64 VGPR)
    const int cg1 = wid & 3;    // col group
    const int rg1 = wid >> 2;   // row group (32 rows)
    long b1f[8][4];
    #pragma unroll
    for (int ks = 0; ks < 8; ++ks)
        #pragma unroll
        for (int n = 0; n < 4; ++n)
            b1f[ks][n] = *reinterpret_cast<const long*>(
                &w2t8[(cg1 * 64 + n * 16 + l15) * 256 + ks * 32 + l4 * 8]);

    // GEMM2 A-frags (w3^T): wave covers w3 cols cgrp*32..+31, h2 rows rhalf*32..+31
    const int cgrp = wid & 3, rhalf = wid >> 2;
    long w3f[8][2];
    #pragma unroll
    for (int ks = 0; ks < 8; ++ks)
        #pragma unroll
        for (int cb = 0; cb < 2; ++cb)
            w3f[ks][cb] = *reinterpret_cast<const long*>(
                &w3t8[(cgrp * 32 + cb * 16 + l15) * 256 + ks * 32 + l4 * 8]);

    const float b4v = sf_b4[0];

    // ---- h1-build constants: thread builds 8B chunk kc of rows rbase+16i ----
    const int kc = tid & 31;
    const int rbase = tid >> 5;
    f32x4 zp[2], wa[2], wb[2];
    #pragma unroll
    for (int h = 0; h < 2; ++h) {
        zp[h] = *reinterpret_cast<const f32x4*>(&zpart[b * HD + kc * 8 + h * 4]);
        wa[h] = *reinterpret_cast<const f32x4*>(&sf_w1[kc * 8 + h * 4]);
        wb[h] = *reinterpret_cast<const f32x4*>(&sf_w1[HD + kc * 8 + h * 4]);
    }

    auto build_store = [&](const float2* xy, unsigned char* buf) {
        #pragma unroll
        for (int it = 0; it < 4; ++it) {
            int row = it * 16 + rbase;
            float s[8];
            #pragma unroll
            for (int h = 0; h < 2; ++h)
                #pragma unroll
                for (int j = 0; j < 4; ++j) {
                    float v = fmaf(xy[it].x, wa[h][j], fmaf(xy[it].y, wb[h][j], zp[h][j]));
                    s[h * 4 + j] = v > 0.f ? v : 0.f;
                }
            uint2 pk;
            pk.x = pack4_fp8(s[0], s[1], s[2], s[3]);
            pk.y = pack4_fp8(s[4], s[5], s[6], s[7]);
            *reinterpret_cast<uint2*>(&buf[row * 256 + ((kc ^ (row & 15)) << 3)]) = pk;
        }
    };

    // prologue: first tile of this half into h1[0]
    {
        float2 xy0[4];
        #pragma unroll
        for (int it = 0; it < 4; ++it)
            xy0[it] = *reinterpret_cast<const float2*>(
                &coords[2 * (tbase * 64 + it * 16 + rbase)]);
        build_store(xy0, h1[0]);
    }
    __syncthreads();

    #pragma unroll 1
    for (int ph = 0; ph < 34; ++ph) {
        const bool doG1 = (ph < 32);
        const bool doG2 = (ph >= 1) && (ph < 33);
        const unsigned char* h1cur = h1[ph & 1];
        const unsigned char* h2prev = h2[(ph + 1) & 1];   // tile ph-1
        unsigned char* h2cur = h2[ph & 1];                // tile ph

        // ---- prefetch next tile's coords ----
        float2 xy[4];
        if (ph < 31) {
            #pragma unroll
            for (int it = 0; it < 4; ++it)
                xy[it] = *reinterpret_cast<const float2*>(
                    &coords[2 * ((tbase + ph + 1) * 64 + it * 16 + rbase)]);
        }

        f32x4 acc1[2][4] = {};
        f32x4 acc2[2][2] = {};

        if (doG1 && doG2) {
            // ---- fused: GEMM1(tile ph) + GEMM2(tile ph-1), interleaved ----
            #pragma unroll
            for (int ks = 0; ks < 8; ++ks) {
                const int ch = ((ks * 4 + l4) ^ l15) << 3;
                long a0 = *reinterpret_cast<const long*>(&h1cur[(rg1 * 32 + l15)      * 256 + ch]);
                long a1 = *reinterpret_cast<const long*>(&h1cur[(rg1 * 32 + 16 + l15) * 256 + ch]);
                long hb0 = *reinterpret_cast<const long*>(&h2prev[(rhalf * 32 + l15)      * 256 + ch]);
                long hb1 = *reinterpret_cast<const long*>(&h2prev[(rhalf * 32 + 16 + l15) * 256 + ch]);
                __builtin_amdgcn_s_setprio(1);
                #pragma unroll
                for (int n = 0; n < 4; ++n) {
                    acc1[0][n] = __builtin_amdgcn_mfma_f32_16x16x32_fp8_fp8(b1f[ks][n], a0, acc1[0][n], 0, 0, 0);
                    acc1[1][n] = __builtin_amdgcn_mfma_f32_16x16x32_fp8_fp8(b1f[ks][n], a1, acc1[1][n], 0, 0, 0);
                }
                #pragma unroll
                for (int cb = 0; cb < 2; ++cb) {
                    acc2[0][cb] = __builtin_amdgcn_mfma_f32_16x16x32_fp8_fp8(w3f[ks][cb], hb0, acc2[0][cb], 0, 0, 0);
                    acc2[1][cb] = __builtin_amdgcn_mfma_f32_16x16x32_fp8_fp8(w3f[ks][cb], hb1, acc2[1][cb], 0, 0, 0);
                }
                __builtin_amdgcn_s_setprio(0);
            }
        } else if (doG1) {
            // ---- phase 0: GEMM1 only ----
            #pragma unroll
            for (int ks = 0; ks < 8; ++ks) {
                const int ch = ((ks * 4 + l4) ^ l15) << 3;
                long a0 = *reinterpret_cast<const long*>(&h1cur[(rg1 * 32 + l15)      * 256 + ch]);
                long a1 = *reinterpret_cast<const long*>(&h1cur[(rg1 * 32 + 16 + l15) * 256 + ch]);
                __builtin_amdgcn_s_setprio(1);
                #pragma unroll
                for (int n = 0; n < 4; ++n) {
                    acc1[0][n] = __builtin_amdgcn_mfma_f32_16x16x32_fp8_fp8(b1f[ks][n], a0, acc1[0][n], 0, 0, 0);
                    acc1[1][n] = __builtin_amdgcn_mfma_f32_16x16x32_fp8_fp8(b1f[ks][n], a1, acc1[1][n], 0, 0, 0);
                }
                __builtin_amdgcn_s_setprio(0);
            }
        } else if (doG2) {
            // ---- phase 32: GEMM2 only ----
            #pragma unroll
            for (int ks = 0; ks < 8; ++ks) {
                const int ch = ((ks * 4 + l4) ^ l15) << 3;
                long hb0 = *reinterpret_cast<const long*>(&h2prev[(rhalf * 32 + l15)      * 256 + ch]);
                long hb1 = *reinterpret_cast<const long*>(&h2prev[(rhalf * 32 + 16 + l15) * 256 + ch]);
                __builtin_amdgcn_s_setprio(1);
                #pragma unroll
                for (int cb = 0; cb < 2; ++cb) {
                    acc2[0][cb] = __builtin_amdgcn_mfma_f32_16x16x32_fp8_fp8(w3f[ks][cb], hb0, acc2[0][cb], 0, 0, 0);
                    acc2[1][cb] = __builtin_amdgcn_mfma_f32_16x16x32_fp8_fp8(w3f[ks][cb], hb1, acc2[1][cb], 0, 0, 0);
                }
                __builtin_amdgcn_s_setprio(0);
            }
        }

        // ---- build h1 for tile ph+1 (VALU; overlaps MFMA drain) ----
        if (ph < 31) build_store(xy, h1[(ph + 1) & 1]);

        // ---- GEMM1 epilogue: h2 = relu(acc1 + b2) -> h2cur (b32 writes) ----
        if (doG1) {
            #pragma unroll
            for (int n = 0; n < 4; ++n) {
                f32x4 b2v = *reinterpret_cast<const f32x4*>(&sf_b2[cg1 * 64 + n * 16 + l4 * 4]);
                #pragma unroll
                for (int m = 0; m < 2; ++m) {
                    int row = rg1 * 32 + m * 16 + l15;
                    int chunk = cg1 * 8 + n * 2 + (l4 >> 1);
                    float x0 = acc1[m][n][0] + b2v[0];
                    float x1 = acc1[m][n][1] + b2v[1];
                    float x2 = acc1[m][n][2] + b2v[2];
                    float x3 = acc1[m][n][3] + b2v[3];
                    x0 = x0 > 0.f ? x0 : 0.f;
                    x1 = x1 > 0.f ? x1 : 0.f;
                    x2 = x2 > 0.f ? x2 : 0.f;
                    x3 = x3 > 0.f ? x3 : 0.f;
                    *reinterpret_cast<unsigned int*>(
                        &h2cur[row * 256 + ((chunk ^ (row & 15)) << 3) + (l4 & 1) * 4]) =
                        pack4_fp8(x0, x1, x2, x3);
                }
            }
        }

        // ---- GEMM2 epilogue: relu + w4 partial dot -> partials[(ph-1)&1] ----
        if (doG2) {
            f32x4 b3v0 = *reinterpret_cast<const f32x4*>(&sf_b3[cgrp * 32 + l4 * 4]);
            f32x4 b3v1 = *reinterpret_cast<const f32x4*>(&sf_b3[cgrp * 32 + 16 + l4 * 4]);
            f32x4 w4v0 = *reinterpret_cast<const f32x4*>(&sf_w4[cgrp * 32 + l4 * 4]);
            f32x4 w4v1 = *reinterpret_cast<const f32x4*>(&sf_w4[cgrp * 32 + 16 + l4 * 4]);
            #pragma unroll
            for (int rb = 0; rb < 2; ++rb) {
                float pp = 0.f;
                #pragma unroll
                for (int i = 0; i < 4; ++i) {
                    float v0 = acc2[rb][0][i] + b3v0[i];
                    float v1 = acc2[rb][1][i] + b3v1[i];
                    v0 = v0 > 0.f ? v0 : 0.f;
                    v1 = v1 > 0.f ? v1 : 0.f;
                    pp = fmaf(v0, w4v0[i], pp);
                    pp = fmaf(v1, w4v1[i], pp);
                }
                partials[(ph - 1) & 1][rhalf * 32 + rb * 16 + l15][cgrp * 4 + l4] = pp;
            }
        }

        // ---- final store for tile ph-2 (wave 0; partials written phase ph-1) ----
        if (ph >= 2 && tid < 64) {
            const f32x4* pr = reinterpret_cast<const f32x4*>(&partials[ph & 1][tid][0]);
            f32x4 ss = pr[0] + pr[1] + pr[2] + pr[3];
            float s = ss[0] + ss[1] + ss[2] + ss[3] + b4v;
            out[b * GG + (tbase + ph - 2) * 64 + tid] = 1.f / (1.f + __expf(-s));
        }

        __syncthreads();
    }
}

// ---------------------------------------------------------------------------
extern "C" void kernel_launch(void* const* d_in, const int* in_sizes, int n_in,
                              void* d_out, int out_size, void* d_ws, size_t ws_size,
                              hipStream_t stream)
{
    const float* features = (const float*)d_in[0];
    const float* coords   = (const float*)d_in[1];
    const float* ce_w1 = (const float*)d_in[2];
    const float* ce_b1 = (const float*)d_in[3];
    const float* ce_w2 = (const float*)d_in[4];
    const float* ce_b2 = (const float*)d_in[5];
    const float* ce_w3 = (const float*)d_in[6];
    const float* ce_b3 = (const float*)d_in[7];
    const float* sf_w1 = (const float*)d_in[8];
    const float* sf_b1 = (const float*)d_in[9];
    const float* sf_w2 = (const float*)d_in[10];
    const float* sf_b2 = (const float*)d_in[11];
    const float* sf_w3 = (const float*)d_in[12];
    const float* sf_b3 = (const float*)d_in[13];
    const float* sf_w4 = (const float*)d_in[14];
    const float* sf_b4 = (const float*)d_in[15];
    float* out = (float*)d_out;

    char* ws = (char*)d_ws;
    float*        zpart = (float*)ws;                             // 256 KB
    unsigned int* w2t8  = (unsigned int*)(ws + 262144);           //  64 KB
    unsigned int* w3t8  = (unsigned int*)(ws + 262144 + 65536);   //  32 KB
    float*        w1t   = (float*)(ws + 262144 + 65536 + 32768);  //   1 MB (optional)
    const size_t need_w1t = (size_t)(262144 + 65536 + 32768) + (size_t)FD * HD * 4;
    float* w1t_ptr = (ws_size >= need_w1t) ? w1t : nullptr;

    hipLaunchKernelGGL(prep_kernel, dim3(1024), dim3(256), 0, stream,
                       ce_w1, sf_w2, sf_w3, w1t_ptr, w2t8, w3t8);
    hipLaunchKernelGGL(ce_kernel, dim3(256), dim3(256), 0, stream,
                       features, ce_w1, w1t_ptr, ce_b1, ce_w2, ce_b2, ce_w3, ce_b3,
                       sf_w1, sf_b1, zpart);
    hipLaunchKernelGGL(field_kernel, dim3(512), dim3(512), 0, stream,
                       coords, sf_w1, zpart,
                       (const unsigned char*)w2t8, sf_b2,
                       (const unsigned char*)w3t8, sf_b3, sf_w4, sf_b4, out);
}

// Round 10
// 202.157 us; speedup vs baseline: 1.8990x; 1.2764x over previous
//
#include <hip/hip_runtime.h>
#include <hip/hip_bf16.h>

typedef __bf16 bf16_t;
typedef __attribute__((ext_vector_type(4))) float f32x4;

#define FD 1024
#define HD 256
#define GG 4096

// pack 4 f32 -> 4 OCP e4m3 bytes (v_cvt_pk_fp8_f32, gfx950 = OCP)
__device__ inline unsigned int pack4_fp8(float a, float b, float c, float d) {
    int v = __builtin_amdgcn_cvt_pk_fp8_f32(a, b, 0, false);
    v = __builtin_amdgcn_cvt_pk_fp8_f32(c, d, v, true);
    return (unsigned int)v;
}

// ---------------------------------------------------------------------------
// prep: w1t = ce_w1^T (fp32, coalesced CE dot); w2t8/w3t8 = fp8 N-major
// ---------------------------------------------------------------------------
__global__ __launch_bounds__(256) void prep_kernel(
    const float* __restrict__ ce_w1,   // [1024,256]
    const float* __restrict__ sf_w2,   // [256,256]
    const float* __restrict__ sf_w3,   // [256,128]
    float* __restrict__ w1t,           // [256,1024]  (may be null)
    unsigned int* __restrict__ w2t8,   // [256 n][256 k] fp8, as u32[16384]
    unsigned int* __restrict__ w3t8)   // [128 n][256 k] fp8, as u32[8192]
{
    int id = blockIdx.x * 256 + threadIdx.x;   // 0..262143
    if (w1t != nullptr) {
        int j = id >> 10, k = id & 1023;
        w1t[id] = ce_w1[k * 256 + j];
    }
    if (id < 16384) {   // w2: n = id>>6, k4 = (id&63)*4
        int n = id >> 6, k4 = (id & 63) << 2;
        w2t8[id] = pack4_fp8(sf_w2[(k4 + 0) * 256 + n], sf_w2[(k4 + 1) * 256 + n],
                             sf_w2[(k4 + 2) * 256 + n], sf_w2[(k4 + 3) * 256 + n]);
    }
    if (id < 8192) {    // w3: n = id>>6, k4 = (id&63)*4
        int n = id >> 6, k4 = (id & 63) << 2;
        w3t8[id] = pack4_fp8(sf_w3[(k4 + 0) * 128 + n], sf_w3[(k4 + 1) * 128 + n],
                             sf_w3[(k4 + 2) * 128 + n], sf_w3[(k4 + 3) * 128 + n]);
    }
}

// ---------------------------------------------------------------------------
// context encoder: one block per batch row; fp32 throughout.
// zpart[b][j] = z_c[b] @ sf_w1[2:] + sf_b1   (bias folded in)
// ---------------------------------------------------------------------------
__global__ __launch_bounds__(256) void ce_kernel(
    const float* __restrict__ features,   // [256,1024]
    const float* __restrict__ ce_w1,      // [1024,256] (fallback path)
    const float* __restrict__ w1t,        // [256,1024] or null
    const float* __restrict__ ce_b1,
    const float* __restrict__ ce_w2, const float* __restrict__ ce_b2,
    const float* __restrict__ ce_w3, const float* __restrict__ ce_b3,
    const float* __restrict__ sf_w1,      // [66,256]
    const float* __restrict__ sf_b1,
    float* __restrict__ zpart)            // [256,256]
{
    __shared__ float fs[FD];
    __shared__ float z1[HD];
    __shared__ float z2[HD / 2];
    __shared__ float zc[64];
    const int b = blockIdx.x, t = threadIdx.x;

    #pragma unroll
    for (int i = 0; i < 4; ++i) fs[t + i * 256] = features[b * FD + t + i * 256];
    __syncthreads();

    // layer 1: 1024 -> 256
    {
        float s = ce_b1[t];
        if (w1t != nullptr) {
            const float4* wr = reinterpret_cast<const float4*>(w1t + t * FD);
            #pragma unroll 4
            for (int k = 0; k < FD / 4; ++k) {
                float4 w = wr[k];
                const float4 f = *reinterpret_cast<const float4*>(&fs[k * 4]);
                s = fmaf(w.x, f.x, s);
                s = fmaf(w.y, f.y, s);
                s = fmaf(w.z, f.z, s);
                s = fmaf(w.w, f.w, s);
            }
        } else {
            #pragma unroll 8
            for (int k = 0; k < FD; ++k) s = fmaf(fs[k], ce_w1[k * 256 + t], s);
        }
        z1[t] = s > 0.f ? s : 0.f;
    }
    __syncthreads();

    // layer 2: 256 -> 128
    if (t < 128) {
        float s = ce_b2[t];
        #pragma unroll 8
        for (int k = 0; k < 256; ++k) s = fmaf(z1[k], ce_w2[k * 128 + t], s);
        z2[t] = s > 0.f ? s : 0.f;
    }
    __syncthreads();

    // layer 3: 128 -> 64 (no relu)
    if (t < 64) {
        float s = ce_b3[t];
        #pragma unroll 8
        for (int k = 0; k < 128; ++k) s = fmaf(z2[k], ce_w3[k * 64 + t], s);
        zc[t] = s;
    }
    __syncthreads();

    // zpart = zc @ sf_w1[2:] + sf_b1
    {
        float s = sf_b1[t];
        #pragma unroll 8
        for (int k = 0; k < 64; ++k) s = fmaf(zc[k], sf_w1[(2 + k) * 256 + t], s);
        zpart[b * HD + t] = s;
    }
}

// ---------------------------------------------------------------------------
// fused field MLP, fp8, weight-stationary, 4-deep pipeline, 1 barrier/2 tiles.
//   grid=256 (1 block/CU), 512 thr (8 waves, 2/SIMD -- unified-VGPR cap).
//   Sub-phase t:  GEMM1(t) || GEMM2(t-2) || build h1(t+2) || store(t-4)
//   Pair {t0, t0+1} then ONE barrier; all cross-wave RAW spans a barrier
//   (h1/h2/partials all 4-deep; indices differ mod 4 within a pair).
//   Meshgrid: xx tile-constant, yy per-thread invariant -> 1 fma/elem build.
//   Bias folded into MFMA C-init (b2 -> acc1, b3 -> acc2).
//   GEMM1: 2 rgrp x 4 cgrp (wave = 32 rows x 64 cols); b1f 64 VGPR.
//   GEMM2: 2 rhalf x 4 cgrp; w3f 32 VGPR.
// ---------------------------------------------------------------------------
__global__ __launch_bounds__(512, 2) void field_kernel(
    const float* __restrict__ coords,   // [4096,2]
    const float* __restrict__ sf_w1,    // [66,256] rows 0,1 used
    const float* __restrict__ zpart,    // [256,256]
    const unsigned char* __restrict__ w2t8, // [256 n][256 k] fp8
    const float* __restrict__ sf_b2,    // [256]
    const unsigned char* __restrict__ w3t8, // [128 n][256 k] fp8
    const float* __restrict__ sf_b3,    // [128]
    const float* __restrict__ sf_w4,    // [128]
    const float* __restrict__ sf_b4,    // [1]
    float* __restrict__ out)            // [256,4096]
{
    __shared__ __attribute__((aligned(128))) unsigned char h1[4][64 * 256];  // 64 KB
    __shared__ __attribute__((aligned(128))) unsigned char h2[4][64 * 256];  // 64 KB
    __shared__ float partials[4][64][20];                                    // 20 KB

    const int b = blockIdx.x;
    const int tid = threadIdx.x;
    const int wid = tid >> 6;
    const int lane = tid & 63;
    const int l15 = lane & 15;
    const int l4 = lane >> 4;

    // ---- resident weights ----
    const int cg1 = wid & 3;    // GEMM1 col group (64 cols)
    const int rg1 = wid >> 2;   // GEMM1 row group (32 rows)
    long b1f[8][4];
    #pragma unroll
    for (int ks = 0; ks < 8; ++ks)
        #pragma unroll
        for (int n = 0; n < 4; ++n)
            b1f[ks][n] = *reinterpret_cast<const long*>(
                &w2t8[(cg1 * 64 + n * 16 + l15) * 256 + ks * 32 + l4 * 8]);

    const int cgrp = wid & 3, rhalf = wid >> 2;
    long w3f[8][2];
    #pragma unroll
    for (int ks = 0; ks < 8; ++ks)
        #pragma unroll
        for (int cb = 0; cb < 2; ++cb)
            w3f[ks][cb] = *reinterpret_cast<const long*>(
                &w3t8[(cgrp * 32 + cb * 16 + l15) * 256 + ks * 32 + l4 * 8]);

    // ---- resident bias / w4 vectors ----
    f32x4 b2r[4];
    #pragma unroll
    for (int n = 0; n < 4; ++n)
        b2r[n] = *reinterpret_cast<const f32x4*>(&sf_b2[cg1 * 64 + n * 16 + l4 * 4]);
    f32x4 b3r[2], w4r[2];
    #pragma unroll
    for (int cb = 0; cb < 2; ++cb) {
        b3r[cb] = *reinterpret_cast<const f32x4*>(&sf_b3[cgrp * 32 + cb * 16 + l4 * 4]);
        w4r[cb] = *reinterpret_cast<const f32x4*>(&sf_w4[cgrp * 32 + cb * 16 + l4 * 4]);
    }
    const float b4v = sf_b4[0];

    // ---- h1-build constants (meshgrid: xx tile-const, yy thread-invariant) ----
    const int kc = tid & 31;           // 8B chunk within row
    const int rbase = tid >> 5;        // row base 0..15 (rows rbase+16*it)
    const int kcs = (kc ^ rbase) << 3; // swizzled byte offset (row&15 == rbase)
    float zpf[8], waf[8], wbf[8];
    #pragma unroll
    for (int j = 0; j < 8; ++j) {
        zpf[j] = zpart[b * HD + kc * 8 + j];
        waf[j] = sf_w1[kc * 8 + j];
        wbf[j] = sf_w1[HD + kc * 8 + j];
    }
    float xvr[4];
    #pragma unroll
    for (int it = 0; it < 4; ++it)
        xvr[it] = coords[2 * (it * 16 + rbase) + 1];   // yy = x[row], tile-invariant

    // GEMM ds_read swizzled offsets per ks (thread-constant)
    int chv[8];
    #pragma unroll
    for (int ks = 0; ks < 8; ++ks) chv[ks] = ((ks * 4 + l4) ^ l15) << 3;

    auto build = [&](int t) {
        unsigned char* buf = h1[t & 3];
        float x0 = coords[t * 128];    // xx tile-constant
        float zc8[8];
        #pragma unroll
        for (int j = 0; j < 8; ++j) zc8[j] = fmaf(x0, waf[j], zpf[j]);
        #pragma unroll
        for (int it = 0; it < 4; ++it) {
            float xv = xvr[it];
            float s[8];
            #pragma unroll
            for (int j = 0; j < 8; ++j) {
                float v = fmaf(xv, wbf[j], zc8[j]);
                s[j] = v > 0.f ? v : 0.f;
            }
            uint2 pk;
            pk.x = pack4_fp8(s[0], s[1], s[2], s[3]);
            pk.y = pack4_fp8(s[4], s[5], s[6], s[7]);
            *reinterpret_cast<uint2*>(&buf[(it * 16 + rbase) * 256 + kcs]) = pk;
        }
    };

    auto subphase = [&](int t) {
        const int tg2 = t - 2;
        const bool g1 = (t < 64);
        const bool g2 = (tg2 >= 0);    // tg2 < 64 guaranteed by loop bound
        f32x4 acc1[2][4];
        f32x4 acc2[2][2];
        if (g1) {
            #pragma unroll
            for (int m = 0; m < 2; ++m)
                #pragma unroll
                for (int n = 0; n < 4; ++n) acc1[m][n] = b2r[n];   // bias C-init
        }
        if (g2) {
            #pragma unroll
            for (int rb = 0; rb < 2; ++rb)
                #pragma unroll
                for (int cb = 0; cb < 2; ++cb) acc2[rb][cb] = b3r[cb];
        }

        const unsigned char* h1c = h1[t & 3];
        const unsigned char* h2p = h2[tg2 & 3];

        if (g1 && g2) {
            #pragma unroll
            for (int ks = 0; ks < 8; ++ks) {
                const int ch = chv[ks];
                long a0 = *reinterpret_cast<const long*>(&h1c[(rg1 * 32 + l15)      * 256 + ch]);
                long a1 = *reinterpret_cast<const long*>(&h1c[(rg1 * 32 + 16 + l15) * 256 + ch]);
                long hb0 = *reinterpret_cast<const long*>(&h2p[(rhalf * 32 + l15)      * 256 + ch]);
                long hb1 = *reinterpret_cast<const long*>(&h2p[(rhalf * 32 + 16 + l15) * 256 + ch]);
                __builtin_amdgcn_s_setprio(1);
                #pragma unroll
                for (int n = 0; n < 4; ++n) {
                    acc1[0][n] = __builtin_amdgcn_mfma_f32_16x16x32_fp8_fp8(b1f[ks][n], a0, acc1[0][n], 0, 0, 0);
                    acc1[1][n] = __builtin_amdgcn_mfma_f32_16x16x32_fp8_fp8(b1f[ks][n], a1, acc1[1][n], 0, 0, 0);
                }
                #pragma unroll
                for (int cb = 0; cb < 2; ++cb) {
                    acc2[0][cb] = __builtin_amdgcn_mfma_f32_16x16x32_fp8_fp8(w3f[ks][cb], hb0, acc2[0][cb], 0, 0, 0);
                    acc2[1][cb] = __builtin_amdgcn_mfma_f32_16x16x32_fp8_fp8(w3f[ks][cb], hb1, acc2[1][cb], 0, 0, 0);
                }
                __builtin_amdgcn_s_setprio(0);
            }
        } else if (g1) {
            #pragma unroll
            for (int ks = 0; ks < 8; ++ks) {
                const int ch = chv[ks];
                long a0 = *reinterpret_cast<const long*>(&h1c[(rg1 * 32 + l15)      * 256 + ch]);
                long a1 = *reinterpret_cast<const long*>(&h1c[(rg1 * 32 + 16 + l15) * 256 + ch]);
                __builtin_amdgcn_s_setprio(1);
                #pragma unroll
                for (int n = 0; n < 4; ++n) {
                    acc1[0][n] = __builtin_amdgcn_mfma_f32_16x16x32_fp8_fp8(b1f[ks][n], a0, acc1[0][n], 0, 0, 0);
                    acc1[1][n] = __builtin_amdgcn_mfma_f32_16x16x32_fp8_fp8(b1f[ks][n], a1, acc1[1][n], 0, 0, 0);
                }
                __builtin_amdgcn_s_setprio(0);
            }
        } else if (g2) {
            #pragma unroll
            for (int ks = 0; ks < 8; ++ks) {
                const int ch = chv[ks];
                long hb0 = *reinterpret_cast<const long*>(&h2p[(rhalf * 32 + l15)      * 256 + ch]);
                long hb1 = *reinterpret_cast<const long*>(&h2p[(rhalf * 32 + 16 + l15) * 256 + ch]);
                __builtin_amdgcn_s_setprio(1);
                #pragma unroll
                for (int cb = 0; cb < 2; ++cb) {
                    acc2[0][cb] = __builtin_amdgcn_mfma_f32_16x16x32_fp8_fp8(w3f[ks][cb], hb0, acc2[0][cb], 0, 0, 0);
                    acc2[1][cb] = __builtin_amdgcn_mfma_f32_16x16x32_fp8_fp8(w3f[ks][cb], hb1, acc2[1][cb], 0, 0, 0);
                }
                __builtin_amdgcn_s_setprio(0);
            }
        }

        // build h1 for tile t+2 (read in the NEXT pair, after the barrier)
        if (t + 2 < 64) build(t + 2);

        // GEMM1 epilogue: h2 = relu(acc1) (bias pre-added) -> h2[t&3]
        if (g1) {
            unsigned char* h2c = h2[t & 3];
            #pragma unroll
            for (int n = 0; n < 4; ++n) {
                #pragma unroll
                for (int m = 0; m < 2; ++m) {
                    int row = rg1 * 32 + m * 16 + l15;
                    int chunk = cg1 * 8 + n * 2 + (l4 >> 1);
                    float x0 = acc1[m][n][0] > 0.f ? acc1[m][n][0] : 0.f;
                    float x1 = acc1[m][n][1] > 0.f ? acc1[m][n][1] : 0.f;
                    float x2 = acc1[m][n][2] > 0.f ? acc1[m][n][2] : 0.f;
                    float x3 = acc1[m][n][3] > 0.f ? acc1[m][n][3] : 0.f;
                    *reinterpret_cast<unsigned int*>(
                        &h2c[row * 256 + ((chunk ^ (row & 15)) << 3) + (l4 & 1) * 4]) =
                        pack4_fp8(x0, x1, x2, x3);
                }
            }
        }

        // GEMM2 epilogue: relu (bias pre-added) + w4 dot -> partials[tg2&3]
        if (g2) {
            #pragma unroll
            for (int rb = 0; rb < 2; ++rb) {
                float pp = 0.f;
                #pragma unroll
                for (int cb = 0; cb < 2; ++cb)
                    #pragma unroll
                    for (int i = 0; i < 4; ++i) {
                        float v = acc2[rb][cb][i] > 0.f ? acc2[rb][cb][i] : 0.f;
                        pp = fmaf(v, w4r[cb][i], pp);
                    }
                partials[tg2 & 3][rhalf * 32 + rb * 16 + l15][cgrp * 4 + l4] = pp;
            }
        }

        // final store for tile t-4 (partials written one pair ago)
        const int tf = t - 4;
        if (tf >= 0 && tid < 64) {
            const f32x4* pr = reinterpret_cast<const f32x4*>(&partials[tf & 3][tid][0]);
            f32x4 ss = pr[0] + pr[1] + pr[2] + pr[3];
            float s = ss[0] + ss[1] + ss[2] + ss[3] + b4v;
            out[b * GG + tf * 64 + tid] = 1.f / (1.f + __expf(-s));
        }
    };

    // prologue: tiles 0 and 1
    build(0);
    build(1);
    __syncthreads();

    #pragma unroll 1
    for (int t0 = 0; t0 < 68; t0 += 2) {
        subphase(t0);
        subphase(t0 + 1);
        __syncthreads();
    }
}

// ---------------------------------------------------------------------------
extern "C" void kernel_launch(void* const* d_in, const int* in_sizes, int n_in,
                              void* d_out, int out_size, void* d_ws, size_t ws_size,
                              hipStream_t stream)
{
    const float* features = (const float*)d_in[0];
    const float* coords   = (const float*)d_in[1];
    const float* ce_w1 = (const float*)d_in[2];
    const float* ce_b1 = (const float*)d_in[3];
    const float* ce_w2 = (const float*)d_in[4];
    const float* ce_b2 = (const float*)d_in[5];
    const float* ce_w3 = (const float*)d_in[6];
    const float* ce_b3 = (const float*)d_in[7];
    const float* sf_w1 = (const float*)d_in[8];
    const float* sf_b1 = (const float*)d_in[9];
    const float* sf_w2 = (const float*)d_in[10];
    const float* sf_b2 = (const float*)d_in[11];
    const float* sf_w3 = (const float*)d_in[12];
    const float* sf_b3 = (const float*)d_in[13];
    const float* sf_w4 = (const float*)d_in[14];
    const float* sf_b4 = (const float*)d_in[15];
    float* out = (float*)d_out;

    char* ws = (char*)d_ws;
    float*        zpart = (float*)ws;                             // 256 KB
    unsigned int* w2t8  = (unsigned int*)(ws + 262144);           //  64 KB
    unsigned int* w3t8  = (unsigned int*)(ws + 262144 + 65536);   //  32 KB
    float*        w1t   = (float*)(ws + 262144 + 65536 + 32768);  //   1 MB (optional)
    const size_t need_w1t = (size_t)(262144 + 65536 + 32768) + (size_t)FD * HD * 4;
    float* w1t_ptr = (ws_size >= need_w1t) ? w1t : nullptr;

    hipLaunchKernelGGL(prep_kernel, dim3(1024), dim3(256), 0, stream,
                       ce_w1, sf_w2, sf_w3, w1t_ptr, w2t8, w3t8);
    hipLaunchKernelGGL(ce_kernel, dim3(256), dim3(256), 0, stream,
                       features, ce_w1, w1t_ptr, ce_b1, ce_w2, ce_b2, ce_w3, ce_b3,
                       sf_w1, sf_b1, zpart);
    hipLaunchKernelGGL(field_kernel, dim3(256), dim3(512), 0, stream,
                       coords, sf_w1, zpart,
                       (const unsigned char*)w2t8, sf_b2,
                       (const unsigned char*)w3t8, sf_b3, sf_w4, sf_b4, out);
}